// Round 9
// baseline (229.686 us; speedup 1.0000x reference)
//
#include <hip/hip_runtime.h>
#include <math.h>

#define PS 6
#define P2 36
#define CI 32
#define OO 32
#define KC 288
#define KCO 9216
#define EPSF 1e-9f
#define LOG2PI_F 1.8378770664093455f

/* workspace float offsets */
#define ZZ_OFF   0u            /* 2,654,208 floats */
#define WT_OFF   2654208u      /* 147,456 floats */
#define PART_OFF 2801664u      /* 1152*1056 = 1,216,512 floats */
#define MS_OFF   4018176u      /* 43,264 float2 = 86,528 floats */

__device__ __forceinline__ int covr(int x){
  int cnt = 0;
#pragma unroll
  for (int r = 0; r < 6; ++r) { int i = x - 2*r; cnt += (i >= 0 && i <= 2) ? 1 : 0; }
  return cnt;
}

/* wT[((k*4+c)*32+o)*4+b] = w[k][o][b][c] */
__global__ __launch_bounds__(256) void wtrans_kernel(const float* __restrict__ w,
                                                     float* __restrict__ wT)
{
  int e = blockIdx.x * 256 + threadIdx.x;   /* 147456 */
  int b = e & 3, o = (e >> 2) & 31, c = (e >> 7) & 3, k = e >> 9;
  wT[e] = w[k*512 + o*16 + b*4 + c];
}

/* ---- K1: partial moments. grid = 1152 (np,k4), block 256 = (q,o) ---- */
template<bool FIRST>
__global__ __launch_bounds__(256, 4) void moments_kernel(
    const float* __restrict__ inp, const float* __restrict__ wT,
    const float* __restrict__ zzg, const float2* __restrict__ msg,
    float* __restrict__ part)
{
  __shared__ float s_pose[72*16];
  __shared__ float s_m[72];    /* FIRST: rr0*act ; else child max */
  __shared__ float s_s[72];    /* else: act/(den+eps) */
  __shared__ float s_red[4*1056];

  const int blk = blockIdx.x;
  const int np = blk >> 2, k4 = blk & 3;
  const int n = np / P2, p = np % P2;
  const int pr = p / PS, pc = p % PS;
  const int t = threadIdx.x;
  const int k0 = k4 * 72;

  const float* ibase = inp + (size_t)n * (196*32*17);
  for (int e = t; e < 72*16; e += 256) {
    int kl = e >> 4, h = e & 15;
    int k = k0 + kl;
    int kk = k >> 5, ci = k & 31;
    s_pose[e] = ibase[(((pr*2 + kk/3)*14 + (pc*2 + kk%3))*32 + ci)*17 + h];
  }
  if (t < 72) {
    int k = k0 + t; int kk = k >> 5, ci = k & 31;
    int x = pr*2 + kk/3, y = pc*2 + kk%3;
    if (FIRST) {
      float a = ibase[((x*14 + y)*32 + ci)*17 + 16];
      s_m[t] = a / (float)(covr(x) * covr(y) * OO);
    } else {
      float2 ms = msg[((size_t)(n*169 + x*13 + y))*32 + ci];
      s_m[t] = ms.x;
      s_s[t] = ms.y;
    }
  }
  __syncthreads();

  const int q = t >> 5, o = t & 31;
  float srr = 0.f;
  float m1[16], m2[16];
#pragma unroll
  for (int j = 0; j < 16; ++j) { m1[j] = 0.f; m2[j] = 0.f; }

  const float* zp = zzg + (size_t)np * KCO + ((size_t)k0 << 5) + o;

  /* software pipeline: prefetch k+1 while computing k */
  float4 A0n, A1n, A2n, A3n, w0n, w1n, w2n, w3n;
  float zn = 0.f;
  {
    int kl = q*9;
    const float4* pk  = (const float4*)s_pose + (kl << 2);
    A0n = pk[0]; A1n = pk[1]; A2n = pk[2]; A3n = pk[3];
    const float4* wkb = (const float4*)wT + ((size_t)(k0 + kl) << 7) + o;
    w0n = wkb[0]; w1n = wkb[32]; w2n = wkb[64]; w3n = wkb[96];
    if (!FIRST) zn = zp[kl << 5];
  }
#pragma unroll
  for (int ks = 0; ks < 9; ++ks) {
    const int kl = q*9 + ks;
    float4 A0 = A0n, A1 = A1n, A2 = A2n, A3 = A3n;
    float4 w0 = w0n, w1 = w1n, w2 = w2n, w3 = w3n;
    float z = zn;
    if (ks < 8) {
      const float4* pk  = (const float4*)s_pose + ((kl+1) << 2);
      A0n = pk[0]; A1n = pk[1]; A2n = pk[2]; A3n = pk[3];
      const float4* wkb = (const float4*)wT + ((size_t)(k0 + kl + 1) << 7) + o;
      w0n = wkb[0]; w1n = wkb[32]; w2n = wkb[64]; w3n = wkb[96];
      if (!FIRST) zn = zp[(kl+1) << 5];
    }
    float rra = FIRST ? s_m[kl] : __expf(z - s_m[kl]) * s_s[kl];
    srr += rra;
    {
      float v0 = A0.x*w0.x + A0.y*w0.y + A0.z*w0.z + A0.w*w0.w;
      float v1 = A0.x*w1.x + A0.y*w1.y + A0.z*w1.z + A0.w*w1.w;
      float v2 = A0.x*w2.x + A0.y*w2.y + A0.z*w2.z + A0.w*w2.w;
      float v3 = A0.x*w3.x + A0.y*w3.y + A0.z*w3.z + A0.w*w3.w;
      float r0=rra*v0, r1=rra*v1, r2=rra*v2, r3=rra*v3;
      m1[0]+=r0; m1[1]+=r1; m1[2]+=r2; m1[3]+=r3;
      m2[0]+=r0*v0; m2[1]+=r1*v1; m2[2]+=r2*v2; m2[3]+=r3*v3;
    }
    {
      float v0 = A1.x*w0.x + A1.y*w0.y + A1.z*w0.z + A1.w*w0.w;
      float v1 = A1.x*w1.x + A1.y*w1.y + A1.z*w1.z + A1.w*w1.w;
      float v2 = A1.x*w2.x + A1.y*w2.y + A1.z*w2.z + A1.w*w2.w;
      float v3 = A1.x*w3.x + A1.y*w3.y + A1.z*w3.z + A1.w*w3.w;
      float r0=rra*v0, r1=rra*v1, r2=rra*v2, r3=rra*v3;
      m1[4]+=r0; m1[5]+=r1; m1[6]+=r2; m1[7]+=r3;
      m2[4]+=r0*v0; m2[5]+=r1*v1; m2[6]+=r2*v2; m2[7]+=r3*v3;
    }
    {
      float v0 = A2.x*w0.x + A2.y*w0.y + A2.z*w0.z + A2.w*w0.w;
      float v1 = A2.x*w1.x + A2.y*w1.y + A2.z*w1.z + A2.w*w1.w;
      float v2 = A2.x*w2.x + A2.y*w2.y + A2.z*w2.z + A2.w*w2.w;
      float v3 = A2.x*w3.x + A2.y*w3.y + A2.z*w3.z + A2.w*w3.w;
      float r0=rra*v0, r1=rra*v1, r2=rra*v2, r3=rra*v3;
      m1[8]+=r0; m1[9]+=r1; m1[10]+=r2; m1[11]+=r3;
      m2[8]+=r0*v0; m2[9]+=r1*v1; m2[10]+=r2*v2; m2[11]+=r3*v3;
    }
    {
      float v0 = A3.x*w0.x + A3.y*w0.y + A3.z*w0.z + A3.w*w0.w;
      float v1 = A3.x*w1.x + A3.y*w1.y + A3.z*w1.z + A3.w*w1.w;
      float v2 = A3.x*w2.x + A3.y*w2.y + A3.z*w2.z + A3.w*w2.w;
      float v3 = A3.x*w3.x + A3.y*w3.y + A3.z*w3.z + A3.w*w3.w;
      float r0=rra*v0, r1=rra*v1, r2=rra*v2, r3=rra*v3;
      m1[12]+=r0; m1[13]+=r1; m1[14]+=r2; m1[15]+=r3;
      m2[12]+=r0*v0; m2[13]+=r1*v1; m2[14]+=r2*v2; m2[15]+=r3*v3;
    }
  }

  /* combine q-pairs in-wave, then 4 wave-groups via LDS */
  srr += __shfl_xor(srr, 32, 64);
#pragma unroll
  for (int j = 0; j < 16; ++j) {
    m1[j] += __shfl_xor(m1[j], 32, 64);
    m2[j] += __shfl_xor(m2[j], 32, 64);
  }
  {
    const int lane = t & 63, wv = t >> 6;
    if (lane < 32) {
      float* rb = s_red + wv*1056 + lane*33;
      rb[0] = srr;
#pragma unroll
      for (int j = 0; j < 16; ++j) { rb[1+j] = m1[j]; rb[17+j] = m2[j]; }
    }
  }
  __syncthreads();
  float* pb = part + (size_t)blk * 1056;
  for (int u = t; u < 1056; u += 256) {
    pb[u] = s_red[u] + s_red[1056+u] + s_red[2112+u] + s_red[3168+u];
  }
}

/* ---- K2: stats (redundant per k4) + zz. grid 1152, block 512 ---- */
template<int IT>
__global__ __launch_bounds__(512, 4) void zzstats_kernel(
    const float* __restrict__ inp, const float* __restrict__ wT,
    const float* __restrict__ part,
    const float* __restrict__ beta_v, const float* __restrict__ beta_a,
    float* __restrict__ zzg)
{
  __shared__ float s_pose[72*16];
  __shared__ float s_mean[512];
  __shared__ float s_i2v[512];
  __shared__ float s_cost[OO];
  __shared__ float s_lvs[OO];
  __shared__ float s_lc[OO];

  const int blk = blockIdx.x;
  const int np = blk >> 2, k4 = blk & 3;
  const int n = np / P2, p = np % P2;
  const int pr = p / PS, pc = p % PS;
  const int t = threadIdx.x;
  const int k0 = k4 * 72;

  const float* ibase = inp + (size_t)n * (196*32*17);
  for (int e = t; e < 72*16; e += 512) {
    int kl = e >> 4, h = e & 15;
    int k = k0 + kl;
    int kk = k >> 5, ci = k & 31;
    s_pose[e] = ibase[(((pr*2 + kk/3)*14 + (pc*2 + kk%3))*32 + ci)*17 + h];
  }

  /* stats: t = (so,h) */
  {
    const int so = t >> 4, h = t & 15;
    const float* pb = part + (size_t)np * 4224 + so*33;
    float rs = pb[0]    + pb[1056]      + pb[2112]      + pb[3168];
    float a1 = pb[1+h]  + pb[1056+1+h]  + pb[2112+1+h]  + pb[3168+1+h];
    float a2 = pb[17+h] + pb[1056+17+h] + pb[2112+17+h] + pb[3168+17+h];
    float S    = rs + EPSF;
    float mean = a1 / S;
    float var  = fmaxf(a2 / S - mean*mean, 0.f) + EPSF;
    float lvh  = __logf(var);
    float ch   = (beta_v[so] + 0.5f * lvh) * rs;
    float lv   = lvh;
#pragma unroll
    for (int d = 1; d < 16; d <<= 1) {
      ch += __shfl_xor(ch, d, 64);
      lv += __shfl_xor(lv, d, 64);
    }
    s_mean[t] = mean;
    s_i2v[t]  = 0.5f / var;
    if (h == 0) { s_cost[so] = ch; s_lvs[so] = lv; }
  }
  __syncthreads();

  if (t < OO) {
    float cm = 0.f;
#pragma unroll
    for (int oi = 0; oi < OO; ++oi) cm += s_cost[oi];
    cm *= (1.f / OO);
    float ssq = 0.f;
#pragma unroll
    for (int oi = 0; oi < OO; ++oi) { float d = s_cost[oi] - cm; ssq += d*d; }
    float sd = sqrtf(ssq * (1.f / OO));
    const float INVT = (IT==0) ? 5.0e-4f : 9.75e-4f;
    float arg = INVT * (beta_a[t] + (cm - s_cost[t]) / (sd + EPSF));
    float aj  = 1.f / (1.f + __expf(-arg));
    s_lc[t] = __logf(aj + EPSF) - 0.5f * (s_lvs[t] + 16.f * LOG2PI_F);
  }
  __syncthreads();

  /* zz rows: kl = i*16 + tq (i=0..3), tail kl = 64+tq for tq<8 */
  {
    const int oz = t & 31;
    const int tq = t >> 5;              /* 0..15 */
    const float lc = s_lc[oz];
    const float4* mo4 = (const float4*)(s_mean + (oz << 4));
    const float4* io4 = (const float4*)(s_i2v  + (oz << 4));
    float4 M0 = mo4[0], M1 = mo4[1], M2 = mo4[2], M3 = mo4[3];
    float4 I0 = io4[0], I1 = io4[1], I2 = io4[2], I3 = io4[3];
    float* zb = zzg + (size_t)np * KCO + ((size_t)k0 << 5);

    float4 w0n, w1n, w2n, w3n;
    {
      const float4* wkb = (const float4*)wT + ((size_t)(k0 + tq) << 7) + oz;
      w0n = wkb[0]; w1n = wkb[32]; w2n = wkb[64]; w3n = wkb[96];
    }
#pragma unroll
    for (int i = 0; i < 5; ++i) {
      if (i == 4 && tq >= 8) break;
      const int kl = (i < 4) ? (i*16 + tq) : (64 + tq);
      float4 w0 = w0n, w1 = w1n, w2 = w2n, w3 = w3n;
      if (i < 4) {
        int kln = (i < 3) ? (kl + 16) : (64 + (tq & 7));
        const float4* wkb = (const float4*)wT + ((size_t)(k0 + kln) << 7) + oz;
        w0n = wkb[0]; w1n = wkb[32]; w2n = wkb[64]; w3n = wkb[96];
      }
      const float4* pk = (const float4*)s_pose + (kl << 2);
      float ssum = 0.f;
      float4 A;
      A = pk[0];
      {
        float x0 = A.x*w0.x + A.y*w0.y + A.z*w0.z + A.w*w0.w;
        float x1 = A.x*w1.x + A.y*w1.y + A.z*w1.z + A.w*w1.w;
        float x2 = A.x*w2.x + A.y*w2.y + A.z*w2.z + A.w*w2.w;
        float x3 = A.x*w3.x + A.y*w3.y + A.z*w3.z + A.w*w3.w;
        float d0 = x0-M0.x, d1 = x1-M0.y, d2 = x2-M0.z, d3 = x3-M0.w;
        ssum += d0*d0*I0.x + d1*d1*I0.y + d2*d2*I0.z + d3*d3*I0.w;
      }
      A = pk[1];
      {
        float x0 = A.x*w0.x + A.y*w0.y + A.z*w0.z + A.w*w0.w;
        float x1 = A.x*w1.x + A.y*w1.y + A.z*w1.z + A.w*w1.w;
        float x2 = A.x*w2.x + A.y*w2.y + A.z*w2.z + A.w*w2.w;
        float x3 = A.x*w3.x + A.y*w3.y + A.z*w3.z + A.w*w3.w;
        float d0 = x0-M1.x, d1 = x1-M1.y, d2 = x2-M1.z, d3 = x3-M1.w;
        ssum += d0*d0*I1.x + d1*d1*I1.y + d2*d2*I1.z + d3*d3*I1.w;
      }
      A = pk[2];
      {
        float x0 = A.x*w0.x + A.y*w0.y + A.z*w0.z + A.w*w0.w;
        float x1 = A.x*w1.x + A.y*w1.y + A.z*w1.z + A.w*w1.w;
        float x2 = A.x*w2.x + A.y*w2.y + A.z*w2.z + A.w*w2.w;
        float x3 = A.x*w3.x + A.y*w3.y + A.z*w3.z + A.w*w3.w;
        float d0 = x0-M2.x, d1 = x1-M2.y, d2 = x2-M2.z, d3 = x3-M2.w;
        ssum += d0*d0*I2.x + d1*d1*I2.y + d2*d2*I2.z + d3*d3*I2.w;
      }
      A = pk[3];
      {
        float x0 = A.x*w0.x + A.y*w0.y + A.z*w0.z + A.w*w0.w;
        float x1 = A.x*w1.x + A.y*w1.y + A.z*w1.z + A.w*w1.w;
        float x2 = A.x*w2.x + A.y*w2.y + A.z*w2.z + A.w*w2.w;
        float x3 = A.x*w3.x + A.y*w3.y + A.z*w3.z + A.w*w3.w;
        float d0 = x0-M3.x, d1 = x1-M3.y, d2 = x2-M3.z, d3 = x3-M3.w;
        ssum += d0*d0*I3.x + d1*d1*I3.y + d2*d2*I3.z + d3*d3*I3.w;
      }
      zb[(kl << 5) + oz] = lc - ssum;
    }
  }
}

/* ---- K3: final stats -> output. grid 288, block 512 ---- */
__global__ __launch_bounds__(512) void statsout_kernel(
    const float* __restrict__ part,
    const float* __restrict__ beta_v, const float* __restrict__ beta_a,
    float* __restrict__ out)
{
  __shared__ float s_cost[OO];
  const int np = blockIdx.x;
  const int t = threadIdx.x;
  const int o = t >> 4, h = t & 15;

  const float* pb = part + (size_t)np * 4224 + o*33;
  float rs = pb[0]    + pb[1056]      + pb[2112]      + pb[3168];
  float a1 = pb[1+h]  + pb[1056+1+h]  + pb[2112+1+h]  + pb[3168+1+h];
  float a2 = pb[17+h] + pb[1056+17+h] + pb[2112+17+h] + pb[3168+17+h];
  float S = rs + EPSF;
  float mean = a1 / S;
  float var  = fmaxf(a2 / S - mean*mean, 0.f) + EPSF;
  float ch   = (beta_v[o] + 0.5f * __logf(var)) * rs;
#pragma unroll
  for (int d = 1; d < 16; d <<= 1) ch += __shfl_xor(ch, d, 64);
  if (h == 0) s_cost[o] = ch;
  __syncthreads();

  float cm = 0.f;
#pragma unroll
  for (int oi = 0; oi < OO; ++oi) cm += s_cost[oi];
  cm *= (1.f / OO);
  float ssq = 0.f;
#pragma unroll
  for (int oi = 0; oi < OO; ++oi) { float d = s_cost[oi] - cm; ssq += d*d; }
  float sd = sqrtf(ssq * (1.f / OO));
  float arg = 1.42625e-3f * (beta_a[o] + (cm - s_cost[o]) / (sd + EPSF));
  float aj  = 1.f / (1.f + __expf(-arg));

  out[((size_t)np*OO + o)*17 + 1 + h] = mean;
  if (h == 0) out[((size_t)np*OO + o)*17] = aj;
}

/* ---- childnorm: 4 parent-slots per (child,ci); writes (m, act/den) ---- */
__global__ __launch_bounds__(256) void childnorm_kernel(
    const float* __restrict__ inp, const float* __restrict__ zzg,
    float2* __restrict__ msg)
{
  const int tg = blockIdx.x * 256 + threadIdx.x;   /* 43264*4 = 173056 */
  const int g = tg >> 2, slot = tg & 3;
  const int n   = g / (169*32);
  const int rem = g % (169*32);
  const int sc  = rem >> 5, ci = rem & 31;
  const int x = sc / 13, y = sc % 13;

  int base = -1; int cnt = 0;
#pragma unroll
  for (int r = 0; r < 6; ++r) {
    int i = x - 2*r;
    if (i < 0 || i > 2) continue;
#pragma unroll
    for (int c2 = 0; c2 < 6; ++c2) {
      int j = y - 2*c2;
      if (j < 0 || j > 2) continue;
      if (cnt == slot) base = (((n*P2 + r*6+c2)*9 + i*3+j)*CI + ci) << 5;
      ++cnt;
    }
  }

  const float4* z4 = (base >= 0) ? (const float4*)(zzg + base) : (const float4*)zzg;
  float4 zv[8];
#pragma unroll
  for (int q = 0; q < 8; ++q) zv[q] = z4[q];

  float m = -1e30f;
  if (base >= 0) {
#pragma unroll
    for (int q = 0; q < 8; ++q) {
      float4 v = zv[q];
      m = fmaxf(m, fmaxf(fmaxf(v.x, v.y), fmaxf(v.z, v.w)));
    }
  }
  m = fmaxf(m, __shfl_xor(m, 1, 64));
  m = fmaxf(m, __shfl_xor(m, 2, 64));

  float den = 0.f;
  if (base >= 0) {
#pragma unroll
    for (int q = 0; q < 8; ++q) {
      float4 v = zv[q];
      den += __expf(v.x-m) + __expf(v.y-m) + __expf(v.z-m) + __expf(v.w-m);
    }
  }
  den += __shfl_xor(den, 1, 64);
  den += __shfl_xor(den, 2, 64);

  if (slot == 0) {
    const float act = inp[(((size_t)n*196 + x*14 + y)*32 + ci)*17 + 16];
    float2 ms; ms.x = m; ms.y = act / (den + EPSF);
    msg[g] = ms;
  }
}

extern "C" void kernel_launch(void* const* d_in, const int* in_sizes, int n_in,
                              void* d_out, int out_size, void* d_ws, size_t ws_size,
                              hipStream_t stream)
{
  (void)in_sizes; (void)n_in; (void)out_size; (void)ws_size;
  const float* inp = (const float*)d_in[0];
  const float* w   = (const float*)d_in[1];
  const float* bv  = (const float*)d_in[2];
  const float* ba  = (const float*)d_in[3];
  float* out = (float*)d_out;
  float* ws  = (float*)d_ws;
  float* zz   = ws + ZZ_OFF;
  float* wT   = ws + WT_OFF;
  float* part = ws + PART_OFF;
  float2* msg = (float2*)(ws + MS_OFF);

  wtrans_kernel<<<576, 256, 0, stream>>>(w, wT);

  moments_kernel<true ><<<1152, 256, 0, stream>>>(inp, wT, zz, msg, part);
  zzstats_kernel<0><<<1152, 512, 0, stream>>>(inp, wT, part, bv, ba, zz);
  childnorm_kernel<<<676, 256, 0, stream>>>(inp, zz, msg);

  moments_kernel<false><<<1152, 256, 0, stream>>>(inp, wT, zz, msg, part);
  zzstats_kernel<1><<<1152, 512, 0, stream>>>(inp, wT, part, bv, ba, zz);
  childnorm_kernel<<<676, 256, 0, stream>>>(inp, zz, msg);

  moments_kernel<false><<<1152, 256, 0, stream>>>(inp, wT, zz, msg, part);
  statsout_kernel<<<288, 512, 0, stream>>>(part, bv, ba, out);
}

// Round 10
// 114.609 us; speedup vs baseline: 2.0041x; 2.0041x over previous
//
#include <hip/hip_runtime.h>
#include <math.h>

#define PS 6
#define P2 36
#define CI 32
#define OO 32
#define KC 288
#define KCO 9216
#define EPSF 1e-9f
#define LOG2PI_F 1.8378770664093455f

/* workspace float offsets */
#define ZZ_OFF   0u            /* 2,654,208 floats */
#define WT_OFF   2654208u      /* 147,456 floats */
#define PART_OFF 2801664u      /* 1152*1056 = 1,216,512 floats */
#define MS_OFF   4018176u      /* 43,264 float2 = 86,528 floats */

__device__ __forceinline__ int covr(int x){
  int cnt = 0;
#pragma unroll
  for (int r = 0; r < 6; ++r) { int i = x - 2*r; cnt += (i >= 0 && i <= 2) ? 1 : 0; }
  return cnt;
}

/* wT[((k*4+c)*32+o)*4+b] = w[k][o][b][c] */
__global__ __launch_bounds__(256) void wtrans_kernel(const float* __restrict__ w,
                                                     float* __restrict__ wT)
{
  int e = blockIdx.x * 256 + threadIdx.x;   /* 147456 */
  int b = e & 3, o = (e >> 2) & 31, c = (e >> 7) & 3, k = e >> 9;
  wT[e] = w[k*512 + o*16 + b*4 + c];
}

/* ---- K1: partial moments. grid = 1152 (np,k4), block 256 = (q,o) ----
   round-7 proven loop body (no explicit pipeline -> no spill);
   IT>0 rra reconstructed as exp(zz - m) * s from childnorm's float2. */
template<bool FIRST>
__global__ __launch_bounds__(256, 5) void moments_kernel(
    const float* __restrict__ inp, const float* __restrict__ wT,
    const float* __restrict__ zzg, const float2* __restrict__ msg,
    float* __restrict__ part)
{
  __shared__ float s_pose[72*16];
  __shared__ float s_m[72];    /* FIRST: rr0*act ; else child max */
  __shared__ float s_s[72];    /* else: act/(den+eps) */
  __shared__ float s_red[4*1056];

  const int blk = blockIdx.x;
  const int np = blk >> 2, k4 = blk & 3;
  const int n = np / P2, p = np % P2;
  const int pr = p / PS, pc = p % PS;
  const int t = threadIdx.x;
  const int k0 = k4 * 72;

  const float* ibase = inp + (size_t)n * (196*32*17);
  for (int e = t; e < 72*16; e += 256) {
    int kl = e >> 4, h = e & 15;
    int k = k0 + kl;
    int kk = k >> 5, ci = k & 31;
    s_pose[e] = ibase[(((pr*2 + kk/3)*14 + (pc*2 + kk%3))*32 + ci)*17 + h];
  }
  if (t < 72) {
    int k = k0 + t; int kk = k >> 5, ci = k & 31;
    int x = pr*2 + kk/3, y = pc*2 + kk%3;
    if (FIRST) {
      float a = ibase[((x*14 + y)*32 + ci)*17 + 16];
      s_m[t] = a / (float)(covr(x) * covr(y) * OO);
    } else {
      float2 ms = msg[((size_t)(n*169 + x*13 + y))*32 + ci];
      s_m[t] = ms.x;
      s_s[t] = ms.y;
    }
  }
  __syncthreads();

  const int q = t >> 5, o = t & 31;
  float srr = 0.f;
  float m1[16], m2[16];
#pragma unroll
  for (int j = 0; j < 16; ++j) { m1[j] = 0.f; m2[j] = 0.f; }

  const float* zp = zzg + (size_t)np * KCO + ((size_t)k0 << 5) + o;

#pragma unroll 3
  for (int ks = 0; ks < 9; ++ks) {
    int kl = q*9 + ks;
    float rra;
    if (FIRST) rra = s_m[kl];
    else       rra = __expf(zp[(size_t)kl << 5] - s_m[kl]) * s_s[kl];
    const float4* pk  = (const float4*)s_pose + (kl << 2);
    const float4* wkb = (const float4*)wT + ((size_t)(k0 + kl) << 7) + o;
    float4 w0 = wkb[0], w1 = wkb[32], w2 = wkb[64], w3 = wkb[96];
    srr += rra;
#pragma unroll
    for (int a = 0; a < 4; ++a) {
      float4 A = pk[a];
      float v0 = A.x*w0.x + A.y*w0.y + A.z*w0.z + A.w*w0.w;
      float v1 = A.x*w1.x + A.y*w1.y + A.z*w1.z + A.w*w1.w;
      float v2 = A.x*w2.x + A.y*w2.y + A.z*w2.z + A.w*w2.w;
      float v3 = A.x*w3.x + A.y*w3.y + A.z*w3.z + A.w*w3.w;
      float r0 = rra*v0, r1 = rra*v1, r2 = rra*v2, r3 = rra*v3;
      m1[a*4+0] += r0;    m1[a*4+1] += r1;    m1[a*4+2] += r2;    m1[a*4+3] += r3;
      m2[a*4+0] += r0*v0; m2[a*4+1] += r1*v1; m2[a*4+2] += r2*v2; m2[a*4+3] += r3*v3;
    }
  }

  /* combine q-pairs in-wave, then 4 wave-groups via LDS */
  srr += __shfl_xor(srr, 32, 64);
#pragma unroll
  for (int j = 0; j < 16; ++j) {
    m1[j] += __shfl_xor(m1[j], 32, 64);
    m2[j] += __shfl_xor(m2[j], 32, 64);
  }
  {
    const int lane = t & 63, wv = t >> 6;
    if (lane < 32) {
      float* rb = s_red + wv*1056 + lane*33;
      rb[0] = srr;
#pragma unroll
      for (int j = 0; j < 16; ++j) { rb[1+j] = m1[j]; rb[17+j] = m2[j]; }
    }
  }
  __syncthreads();
  float* pb = part + (size_t)blk * 1056;
  for (int u = t; u < 1056; u += 256) {
    pb[u] = s_red[u] + s_red[1056+u] + s_red[2112+u] + s_red[3168+u];
  }
}

/* ---- K2: stats (redundant per k4) + zz. grid 1152, block 512 ---- */
template<int IT>
__global__ __launch_bounds__(512, 4) void zzstats_kernel(
    const float* __restrict__ inp, const float* __restrict__ wT,
    const float* __restrict__ part,
    const float* __restrict__ beta_v, const float* __restrict__ beta_a,
    float* __restrict__ zzg)
{
  __shared__ float s_pose[72*16];
  __shared__ float s_mean[512];
  __shared__ float s_i2v[512];
  __shared__ float s_cost[OO];
  __shared__ float s_lvs[OO];
  __shared__ float s_lc[OO];

  const int blk = blockIdx.x;
  const int np = blk >> 2, k4 = blk & 3;
  const int n = np / P2, p = np % P2;
  const int pr = p / PS, pc = p % PS;
  const int t = threadIdx.x;
  const int k0 = k4 * 72;

  const float* ibase = inp + (size_t)n * (196*32*17);
  for (int e = t; e < 72*16; e += 512) {
    int kl = e >> 4, h = e & 15;
    int k = k0 + kl;
    int kk = k >> 5, ci = k & 31;
    s_pose[e] = ibase[(((pr*2 + kk/3)*14 + (pc*2 + kk%3))*32 + ci)*17 + h];
  }

  /* stats: t = (so,h) */
  {
    const int so = t >> 4, h = t & 15;
    const float* pb = part + (size_t)np * 4224 + so*33;
    float rs = pb[0]    + pb[1056]      + pb[2112]      + pb[3168];
    float a1 = pb[1+h]  + pb[1056+1+h]  + pb[2112+1+h]  + pb[3168+1+h];
    float a2 = pb[17+h] + pb[1056+17+h] + pb[2112+17+h] + pb[3168+17+h];
    float S    = rs + EPSF;
    float mean = a1 / S;
    float var  = fmaxf(a2 / S - mean*mean, 0.f) + EPSF;
    float lvh  = __logf(var);
    float ch   = (beta_v[so] + 0.5f * lvh) * rs;
    float lv   = lvh;
#pragma unroll
    for (int d = 1; d < 16; d <<= 1) {
      ch += __shfl_xor(ch, d, 64);
      lv += __shfl_xor(lv, d, 64);
    }
    s_mean[t] = mean;
    s_i2v[t]  = 0.5f / var;
    if (h == 0) { s_cost[so] = ch; s_lvs[so] = lv; }
  }
  __syncthreads();

  if (t < OO) {
    float cm = 0.f;
#pragma unroll
    for (int oi = 0; oi < OO; ++oi) cm += s_cost[oi];
    cm *= (1.f / OO);
    float ssq = 0.f;
#pragma unroll
    for (int oi = 0; oi < OO; ++oi) { float d = s_cost[oi] - cm; ssq += d*d; }
    float sd = sqrtf(ssq * (1.f / OO));
    const float INVT = (IT==0) ? 5.0e-4f : 9.75e-4f;
    float arg = INVT * (beta_a[t] + (cm - s_cost[t]) / (sd + EPSF));
    float aj  = 1.f / (1.f + __expf(-arg));
    s_lc[t] = __logf(aj + EPSF) - 0.5f * (s_lvs[t] + 16.f * LOG2PI_F);
  }
  __syncthreads();

  /* zz rows: kl = i*16 + tq (i=0..3), tail kl = 64+tq for tq<8 */
  {
    const int oz = t & 31;
    const int tq = t >> 5;              /* 0..15 */
    const float lc = s_lc[oz];
    const float4* mo4 = (const float4*)(s_mean + (oz << 4));
    const float4* io4 = (const float4*)(s_i2v  + (oz << 4));
    float4 M0 = mo4[0], M1 = mo4[1], M2 = mo4[2], M3 = mo4[3];
    float4 I0 = io4[0], I1 = io4[1], I2 = io4[2], I3 = io4[3];
    float* zb = zzg + (size_t)np * KCO + ((size_t)k0 << 5);

    float4 w0n, w1n, w2n, w3n;
    {
      const float4* wkb = (const float4*)wT + ((size_t)(k0 + tq) << 7) + oz;
      w0n = wkb[0]; w1n = wkb[32]; w2n = wkb[64]; w3n = wkb[96];
    }
#pragma unroll
    for (int i = 0; i < 5; ++i) {
      if (i == 4 && tq >= 8) break;
      const int kl = (i < 4) ? (i*16 + tq) : (64 + tq);
      float4 w0 = w0n, w1 = w1n, w2 = w2n, w3 = w3n;
      if (i < 4) {
        int kln = (i < 3) ? (kl + 16) : (64 + (tq & 7));
        const float4* wkb = (const float4*)wT + ((size_t)(k0 + kln) << 7) + oz;
        w0n = wkb[0]; w1n = wkb[32]; w2n = wkb[64]; w3n = wkb[96];
      }
      const float4* pk = (const float4*)s_pose + (kl << 2);
      float ssum = 0.f;
      float4 A;
      A = pk[0];
      {
        float x0 = A.x*w0.x + A.y*w0.y + A.z*w0.z + A.w*w0.w;
        float x1 = A.x*w1.x + A.y*w1.y + A.z*w1.z + A.w*w1.w;
        float x2 = A.x*w2.x + A.y*w2.y + A.z*w2.z + A.w*w2.w;
        float x3 = A.x*w3.x + A.y*w3.y + A.z*w3.z + A.w*w3.w;
        float d0 = x0-M0.x, d1 = x1-M0.y, d2 = x2-M0.z, d3 = x3-M0.w;
        ssum += d0*d0*I0.x + d1*d1*I0.y + d2*d2*I0.z + d3*d3*I0.w;
      }
      A = pk[1];
      {
        float x0 = A.x*w0.x + A.y*w0.y + A.z*w0.z + A.w*w0.w;
        float x1 = A.x*w1.x + A.y*w1.y + A.z*w1.z + A.w*w1.w;
        float x2 = A.x*w2.x + A.y*w2.y + A.z*w2.z + A.w*w2.w;
        float x3 = A.x*w3.x + A.y*w3.y + A.z*w3.z + A.w*w3.w;
        float d0 = x0-M1.x, d1 = x1-M1.y, d2 = x2-M1.z, d3 = x3-M1.w;
        ssum += d0*d0*I1.x + d1*d1*I1.y + d2*d2*I1.z + d3*d3*I1.w;
      }
      A = pk[2];
      {
        float x0 = A.x*w0.x + A.y*w0.y + A.z*w0.z + A.w*w0.w;
        float x1 = A.x*w1.x + A.y*w1.y + A.z*w1.z + A.w*w1.w;
        float x2 = A.x*w2.x + A.y*w2.y + A.z*w2.z + A.w*w2.w;
        float x3 = A.x*w3.x + A.y*w3.y + A.z*w3.z + A.w*w3.w;
        float d0 = x0-M2.x, d1 = x1-M2.y, d2 = x2-M2.z, d3 = x3-M2.w;
        ssum += d0*d0*I2.x + d1*d1*I2.y + d2*d2*I2.z + d3*d3*I2.w;
      }
      A = pk[3];
      {
        float x0 = A.x*w0.x + A.y*w0.y + A.z*w0.z + A.w*w0.w;
        float x1 = A.x*w1.x + A.y*w1.y + A.z*w1.z + A.w*w1.w;
        float x2 = A.x*w2.x + A.y*w2.y + A.z*w2.z + A.w*w2.w;
        float x3 = A.x*w3.x + A.y*w3.y + A.z*w3.z + A.w*w3.w;
        float d0 = x0-M3.x, d1 = x1-M3.y, d2 = x2-M3.z, d3 = x3-M3.w;
        ssum += d0*d0*I3.x + d1*d1*I3.y + d2*d2*I3.z + d3*d3*I3.w;
      }
      zb[(kl << 5) + oz] = lc - ssum;
    }
  }
}

/* ---- K3: final stats -> output. grid 288, block 512 ---- */
__global__ __launch_bounds__(512) void statsout_kernel(
    const float* __restrict__ part,
    const float* __restrict__ beta_v, const float* __restrict__ beta_a,
    float* __restrict__ out)
{
  __shared__ float s_cost[OO];
  const int np = blockIdx.x;
  const int t = threadIdx.x;
  const int o = t >> 4, h = t & 15;

  const float* pb = part + (size_t)np * 4224 + o*33;
  float rs = pb[0]    + pb[1056]      + pb[2112]      + pb[3168];
  float a1 = pb[1+h]  + pb[1056+1+h]  + pb[2112+1+h]  + pb[3168+1+h];
  float a2 = pb[17+h] + pb[1056+17+h] + pb[2112+17+h] + pb[3168+17+h];
  float S = rs + EPSF;
  float mean = a1 / S;
  float var  = fmaxf(a2 / S - mean*mean, 0.f) + EPSF;
  float ch   = (beta_v[o] + 0.5f * __logf(var)) * rs;
#pragma unroll
  for (int d = 1; d < 16; d <<= 1) ch += __shfl_xor(ch, d, 64);
  if (h == 0) s_cost[o] = ch;
  __syncthreads();

  float cm = 0.f;
#pragma unroll
  for (int oi = 0; oi < OO; ++oi) cm += s_cost[oi];
  cm *= (1.f / OO);
  float ssq = 0.f;
#pragma unroll
  for (int oi = 0; oi < OO; ++oi) { float d = s_cost[oi] - cm; ssq += d*d; }
  float sd = sqrtf(ssq * (1.f / OO));
  float arg = 1.42625e-3f * (beta_a[o] + (cm - s_cost[o]) / (sd + EPSF));
  float aj  = 1.f / (1.f + __expf(-arg));

  out[((size_t)np*OO + o)*17 + 1 + h] = mean;
  if (h == 0) out[((size_t)np*OO + o)*17] = aj;
}

/* ---- childnorm: 4 parent-slots per (child,ci); writes (m, act/den) ---- */
__global__ __launch_bounds__(256) void childnorm_kernel(
    const float* __restrict__ inp, const float* __restrict__ zzg,
    float2* __restrict__ msg)
{
  const int tg = blockIdx.x * 256 + threadIdx.x;   /* 43264*4 = 173056 */
  const int g = tg >> 2, slot = tg & 3;
  const int n   = g / (169*32);
  const int rem = g % (169*32);
  const int sc  = rem >> 5, ci = rem & 31;
  const int x = sc / 13, y = sc % 13;

  int base = -1; int cnt = 0;
#pragma unroll
  for (int r = 0; r < 6; ++r) {
    int i = x - 2*r;
    if (i < 0 || i > 2) continue;
#pragma unroll
    for (int c2 = 0; c2 < 6; ++c2) {
      int j = y - 2*c2;
      if (j < 0 || j > 2) continue;
      if (cnt == slot) base = (((n*P2 + r*6+c2)*9 + i*3+j)*CI + ci) << 5;
      ++cnt;
    }
  }

  const float4* z4 = (base >= 0) ? (const float4*)(zzg + base) : (const float4*)zzg;
  float4 zv[8];
#pragma unroll
  for (int q = 0; q < 8; ++q) zv[q] = z4[q];

  float m = -1e30f;
  if (base >= 0) {
#pragma unroll
    for (int q = 0; q < 8; ++q) {
      float4 v = zv[q];
      m = fmaxf(m, fmaxf(fmaxf(v.x, v.y), fmaxf(v.z, v.w)));
    }
  }
  m = fmaxf(m, __shfl_xor(m, 1, 64));
  m = fmaxf(m, __shfl_xor(m, 2, 64));

  float den = 0.f;
  if (base >= 0) {
#pragma unroll
    for (int q = 0; q < 8; ++q) {
      float4 v = zv[q];
      den += __expf(v.x-m) + __expf(v.y-m) + __expf(v.z-m) + __expf(v.w-m);
    }
  }
  den += __shfl_xor(den, 1, 64);
  den += __shfl_xor(den, 2, 64);

  if (slot == 0) {
    const float act = inp[(((size_t)n*196 + x*14 + y)*32 + ci)*17 + 16];
    float2 ms; ms.x = m; ms.y = act / (den + EPSF);
    msg[g] = ms;
  }
}

extern "C" void kernel_launch(void* const* d_in, const int* in_sizes, int n_in,
                              void* d_out, int out_size, void* d_ws, size_t ws_size,
                              hipStream_t stream)
{
  (void)in_sizes; (void)n_in; (void)out_size; (void)ws_size;
  const float* inp = (const float*)d_in[0];
  const float* w   = (const float*)d_in[1];
  const float* bv  = (const float*)d_in[2];
  const float* ba  = (const float*)d_in[3];
  float* out = (float*)d_out;
  float* ws  = (float*)d_ws;
  float* zz   = ws + ZZ_OFF;
  float* wT   = ws + WT_OFF;
  float* part = ws + PART_OFF;
  float2* msg = (float2*)(ws + MS_OFF);

  wtrans_kernel<<<576, 256, 0, stream>>>(w, wT);

  moments_kernel<true ><<<1152, 256, 0, stream>>>(inp, wT, zz, msg, part);
  zzstats_kernel<0><<<1152, 512, 0, stream>>>(inp, wT, part, bv, ba, zz);
  childnorm_kernel<<<676, 256, 0, stream>>>(inp, zz, msg);

  moments_kernel<false><<<1152, 256, 0, stream>>>(inp, wT, zz, msg, part);
  zzstats_kernel<1><<<1152, 512, 0, stream>>>(inp, wT, part, bv, ba, zz);
  childnorm_kernel<<<676, 256, 0, stream>>>(inp, zz, msg);

  moments_kernel<false><<<1152, 256, 0, stream>>>(inp, wT, zz, msg, part);
  statsout_kernel<<<288, 512, 0, stream>>>(part, bv, ba, out);
}